// Round 10
// baseline (178.490 us; speedup 1.0000x reference)
//
#include <hip/hip_runtime.h>
#include <hip/hip_bf16.h>

// ---------------------------------------------------------------------------
// GCN layer: out = D^{-1/2} (A_set + I) D^{-1/2} @ (x @ W) + bias
// Pipeline (5 dispatches this round — adj split out as a MEASUREMENT):
//   memset mask (8MB)
//   adj: edge atomicOr pass run x2 (idempotent!) -- amplification probe.
//     dur = edge_read + 2T. Visible in top-5 iff T >= ~22us, which is
//     exactly the GO/NO-GO threshold for a bucket-sort adjacency rewrite
//     (~16us est). Next round reverts the x2 either way.
//   prep: cast x->bf16 | transpose W | pads.
//   fused_mid: [gemm 64x128 MFMA BK=64 XOR-swizzled B | build_ell].
//   spmm: r9 core (quarter-D XCD-pinned, LDS dinv table) + cond second-half
//     ji staging (deg>=65, wave-uniform) + unroll 16.
//   Budget model (r9): fill 46 + memset 1.4 + front ~29 + mid ~20 + spmm
//     ~30 + overhead ~5 = ~130 vs 150.7 measured -> ~20us unexplained,
//     prime suspect = the 1M random device-scope atomics. This round
//     measures them.
// ---------------------------------------------------------------------------

#define ELL_STRIDE 128

typedef __attribute__((ext_vector_type(8))) short bf16x8;
typedef __attribute__((ext_vector_type(4))) float f32x4;
typedef __attribute__((ext_vector_type(2))) float f32x2;

__device__ __forceinline__ unsigned short f2bf(float f) {
  unsigned u = __float_as_uint(f);
  u = (u + 0x7fff + ((u >> 16) & 1)) >> 16;  // RNE
  return (unsigned short)u;
}
__device__ __forceinline__ float bflo(unsigned u) {
  return __uint_as_float(u << 16);
}
__device__ __forceinline__ float bfhi(unsigned u) {
  return __uint_as_float(u & 0xffff0000u);
}

// ---- adj: build_adj atomicOr bitmask, run x2 for measurement (idempotent).
__global__ __launch_bounds__(256) void adj_kernel(
    const int* __restrict__ ei, unsigned* __restrict__ mask, int n_edges,
    int words) {
  const int e = blockIdx.x * 256 + threadIdx.x;
  if (e >= n_edges) return;
  const int u = ei[e];
  const int v = ei[e + n_edges];
  unsigned* au = &mask[(size_t)u * words + (v >> 5)];
  unsigned* av = &mask[(size_t)v * words + (u >> 5)];
  const unsigned bu = 1u << (v & 31);
  const unsigned bv = 1u << (u & 31);
  // pass 1
  atomicOr(au, bu);
  atomicOr(av, bv);
  // pass 2 (measurement duplicate -- atomicOr is idempotent; swapped order
  // so nothing can merge them)
  atomicOr(av, bv);
  atomicOr(au, bu);
}

// ---- prep: [0,cb): cast x->bf16   [cb,cb+tb): transpose W   [last]: pads
__global__ __launch_bounds__(256) void prep_kernel(
    const float* __restrict__ x, unsigned short* __restrict__ xb, int n4,
    const float* __restrict__ W, unsigned short* __restrict__ Wt, int K, int N,
    unsigned short* __restrict__ Hs, float* __restrict__ dinv, int n_nodes,
    int cast_blocks, int tr_blocks) {
  const int bid = blockIdx.x;
  if (bid < cast_blocks) {
    const int t = bid * 256 + threadIdx.x;
    if (t < n4) {
      float4 v = ((const float4*)x)[t];
      ushort4 o;
      o.x = f2bf(v.x); o.y = f2bf(v.y); o.z = f2bf(v.z); o.w = f2bf(v.w);
      ((ushort4*)xb)[t] = o;
    }
    return;
  }
  if (bid < cast_blocks + tr_blocks) {
    // transpose+cast: W[K][N] fp32 -> Wt[N][K] bf16, 32x32 tiles
    __shared__ float tile[32][33];
    const int b = bid - cast_blocks;
    const int bx = b & ((N >> 5) - 1);
    const int by = b >> (31 - __builtin_clz(N >> 5));
    const int tx = threadIdx.x & 31;
    const int ty = threadIdx.x >> 5;  // 0..7
#pragma unroll
    for (int r = 0; r < 4; ++r)
      tile[ty + 8 * r][tx] = W[(size_t)(by * 32 + ty + 8 * r) * N + bx * 32 + tx];
    __syncthreads();
#pragma unroll
    for (int r = 0; r < 4; ++r)
      Wt[(size_t)(bx * 32 + ty + 8 * r) * K + by * 32 + tx] =
          f2bf(tile[tx][ty + 8 * r]);
    return;
  }
  // zero the ELL pad row Hs[n_nodes][:] and its scale dinv[n_nodes]
  {
    const int t = threadIdx.x;
    if (t < (N >> 1)) ((unsigned*)(Hs + (size_t)n_nodes * N))[t] = 0;
    if (t == 0) dinv[n_nodes] = 0.f;
  }
}

// ---- fused mid: [0,gb): gemm 64x128 BK=64   [gb..): build_ell (wave/node)
__global__ __launch_bounds__(256) void fused_mid_kernel(
    const unsigned short* __restrict__ xb,  // [M][K] bf16
    const unsigned short* __restrict__ Wt,  // [N][K] bf16
    unsigned short* __restrict__ Hs,        // [M+1][N] bf16 (unscaled)
    const unsigned* __restrict__ mask, unsigned short* __restrict__ ell,
    int* __restrict__ deg, float* __restrict__ dinv,
    int M, int N, int K, int words, int gemm_blocks, int nbx_sh) {
  // 64x128 tile, BK=64, 4 waves 2x2, wave tile 32x64 (acc[2][4] 16x16x32).
  // 512 blocks -> 2+ blocks/CU resident. B staged with XOR source
  // pre-swizzle (stride-128B fragment read spans all 8 bank-quads;
  // global_load_lds forces a linear LDS dest so swizzle the source).
  __shared__ unsigned short As[512 * 8];
  __shared__ unsigned short Bs[1024 * 8];

  const int tid = threadIdx.x;
  const int bid = blockIdx.x;

  if (bid < gemm_blocks) {
    const int wave = tid >> 6;
    const int lane = tid & 63;
    const int q = lane >> 4;   // quad
    const int c = lane & 15;
    const int bx = bid & ((1 << nbx_sh) - 1);
    const int by = bid >> nbx_sh;
    const int m0 = by * 64;
    const int n0 = bx * 128;
    const int wr = wave >> 1, wc = wave & 1;

    f32x4 acc[2][4] = {};

    for (int k0 = 0; k0 < K; k0 += 64) {
#pragma unroll
      for (int t = 0; t < 2; ++t) {
        const int sbase = t * 256 + wave * 64;
        const int s = sbase + lane;
        const unsigned short* g =
            xb + (size_t)(m0 + (s & 63)) * K + k0 + (s >> 6) * 8;
        __builtin_amdgcn_global_load_lds(
            (const __attribute__((address_space(1))) void*)g,
            (__attribute__((address_space(3))) void*)(As + sbase * 8), 16, 0, 0);
      }
#pragma unroll
      for (int t = 0; t < 4; ++t) {
        const int sbase = t * 256 + wave * 64;
        const int s = sbase + lane;
        const int bn = s >> 3;
        const int bk = (s & 7) ^ (bn & 7);  // XOR-swizzled source (same 128B seg)
        const unsigned short* g =
            Wt + (size_t)(n0 + bn) * K + k0 + bk * 8;
        __builtin_amdgcn_global_load_lds(
            (const __attribute__((address_space(1))) void*)g,
            (__attribute__((address_space(3))) void*)(Bs + sbase * 8), 16, 0, 0);
      }
      __syncthreads();

#pragma unroll
      for (int kk = 0; kk < 2; ++kk) {
        bf16x8 a[2], b[4];
#pragma unroll
        for (int tm = 0; tm < 2; ++tm) {
          const int row = wr * 32 + tm * 16 + c;
          a[tm] = *(const bf16x8*)(As + (((kk * 4 + q) * 64) + row) * 8);
        }
#pragma unroll
        for (int tn = 0; tn < 4; ++tn) {
          const int n = wc * 64 + tn * 16 + c;
          b[tn] = *(const bf16x8*)(Bs + (n * 8 + ((kk * 4 + q) ^ (n & 7))) * 8);
        }
#pragma unroll
        for (int tm = 0; tm < 2; ++tm)
#pragma unroll
          for (int tn = 0; tn < 4; ++tn)
            acc[tm][tn] = __builtin_amdgcn_mfma_f32_16x16x32_bf16(
                a[tm], b[tn], acc[tm][tn], 0, 0, 0);
      }
      __syncthreads();
    }

    // C/D mapping: col=lane&15, row=quad*4+reg ; unscaled store
#pragma unroll
    for (int tm = 0; tm < 2; ++tm) {
#pragma unroll
      for (int r = 0; r < 4; ++r) {
        const int grow = m0 + wr * 32 + tm * 16 + q * 4 + r;
#pragma unroll
        for (int tn = 0; tn < 4; ++tn) {
          const int gcol = n0 + wc * 64 + tn * 16 + c;
          Hs[(size_t)grow * N + gcol] = f2bf(acc[tm][tn][r]);
        }
      }
    }
    return;
  }

  // ---- build_ell: one wave per node, popcount + lane prefix-scan.
  {
    const int wave = tid >> 6, lane = tid & 63;
    const int node = (bid - gemm_blocks) * 4 + wave;
    const unsigned* __restrict__ row = mask + (size_t)node * words;
    unsigned short* __restrict__ out = ell + (size_t)node * ELL_STRIDE;

    int running = 0;
    for (int r = 0; r < words; r += 64) {
      const int w = r + lane;
      unsigned bits = row[w];
      const int cnt = __popc(bits);
      int x = cnt;
#pragma unroll
      for (int d = 1; d < 64; d <<= 1) {
        int y = __shfl_up(x, d, 64);
        if (lane >= d) x += y;
      }
      int pos = running + x - cnt;
      while (bits) {
        const int b = __builtin_ctz(bits);
        bits &= bits - 1;
        if (pos < ELL_STRIDE) out[pos] = (unsigned short)((w << 5) + b);
        ++pos;
      }
      running += __shfl(x, 63, 64);
    }
    // self entry at [running], pads (index M -> dinv 0, zero row) after
    for (int p = running + lane; p < ELL_STRIDE; p += 64)
      out[p] = (unsigned short)(p == running ? node : M);
    if (lane == 0) {
      const int dd = running + 1;  // + self
      deg[node] = dd < ELL_STRIDE ? dd : ELL_STRIDE;
      dinv[node] = rsqrtf((float)running + 1.0f);
    }
  }
}

// ---- spmm: grid 4*(n/16) blocks x 1024 thr; wave = one node-quarter.
// qt = bid&3 (bid%8 XCD round-robin -> quarter k on XCDs {k,k+4}, 2.1MB
// L2-resident). Block stages dinv[8193] (32KB) into LDS once, coalesced;
// ji built from scattered LDS reads. NEW: second ji half staged only when
// deg >= 65 (wave-uniform) -- ~half the waves skip a global load + LDS
// pass; unroll 16 for deeper MLP.
__global__ __launch_bounds__(1024) void spmm_kernel(
    const unsigned short* __restrict__ ell, const int* __restrict__ deg,
    const float* __restrict__ dinv, const unsigned short* __restrict__ Hs,
    const float* __restrict__ bias, float* __restrict__ out, int n, int D) {
  __shared__ float sdinv[8193];
  __shared__ uint2 ji[16][ELL_STRIDE];
  const int tid = threadIdx.x;
  const int wave = tid >> 6, lane = tid & 63;
  const int bid = blockIdx.x;
  const int qt = bid & 3;                     // quarter, XCD-pinned
  const int i = (bid >> 2) * 16 + wave;       // node (n divisible by 16)
  const unsigned rowbytes = (unsigned)(D * 2);

  const int d = deg[i];            // includes the self entry (wave-uniform)
  for (int t = tid; t < n + 1; t += 1024) sdinv[t] = dinv[t];
  __syncthreads();

  {  // stage (byte offset, dinv[j]) — scattered LDS lookups, cheap
    const unsigned j0 = ell[(size_t)i * ELL_STRIDE + lane];
    ji[wave][lane] = make_uint2(j0 * rowbytes, __float_as_uint(sdinv[j0]));
    if (d >= 65) {  // wave-uniform: second half only when the loop reads it
      const unsigned j1 = ell[(size_t)i * ELL_STRIDE + 64 + lane];
      ji[wave][64 + lane] = make_uint2(j1 * rowbytes, __float_as_uint(sdinv[j1]));
    }
  }
  const float di = sdinv[i];
  const int kmax = (d + 7) & ~7;   // ELL pads (dinv 0, zero row) cover tail

  // this wave reads bytes [qt*256, qt*256+256) of each row: 4B per lane
  const char* __restrict__ hb = (const char*)Hs + qt * 256 + lane * 4;
  float a0 = 0.f, a1 = 0.f;

#pragma unroll 16
  for (int k = 0; k < kmax; ++k) {
    const uint2 e = ji[wave][k];  // uniform addr -> LDS broadcast
    const float dj = __uint_as_float(e.y);
    const unsigned hv = *(const unsigned*)(hb + e.x);
    a0 += dj * bflo(hv);
    a1 += dj * bfhi(hv);
  }

  const int col = qt * (D >> 2) + lane * 2;
  const float2 b = *(const float2*)(bias + col);
  f32x2 o;
  o.x = di * a0 + b.x;
  o.y = di * a1 + b.y;
  __builtin_nontemporal_store(o, (f32x2*)(out + (size_t)i * D + col));
}

extern "C" void kernel_launch(void* const* d_in, const int* in_sizes, int n_in,
                              void* d_out, int out_size, void* d_ws, size_t ws_size,
                              hipStream_t stream) {
  const float* x    = (const float*)d_in[0];
  const int*   ei   = (const int*)d_in[1];
  const float* W    = (const float*)d_in[2];
  const float* bias = (const float*)d_in[3];
  float* out = (float*)d_out;

  const int d_out_dim = in_sizes[3];             // 512
  const int d_in_dim  = in_sizes[2] / d_out_dim; // 512
  const int n_nodes   = in_sizes[0] / d_in_dim;  // 8192
  const int n_edges   = in_sizes[1] / 2;         // 262144
  const int words     = (n_nodes + 31) / 32;     // 256

  // workspace layout (bytes)
  char* ws = (char*)d_ws;
  size_t off = 0;
  unsigned* mask = (unsigned*)(ws + off); off += (size_t)n_nodes * words * 4;       // 8 MB
  int* deg       = (int*)(ws + off);      off += (size_t)n_nodes * 4;               // 32 KB
  float* dinv    = (float*)(ws + off);    off += (size_t)(n_nodes + 1) * 4;         // 32 KB + pad
  unsigned short* ell = (unsigned short*)(ws + off); off += (size_t)n_nodes * ELL_STRIDE * 2; // 2 MB
  unsigned short* xb  = (unsigned short*)(ws + off); off += (size_t)n_nodes * d_in_dim * 2;   // 8 MB
  unsigned short* Wt  = (unsigned short*)(ws + off); off += (size_t)d_in_dim * d_out_dim * 2; // 512 KB
  unsigned short* Hs  = (unsigned short*)(ws + off);
  off += (size_t)(n_nodes + 1) * d_out_dim * 2;  // 8 MB + pad row

  hipMemsetAsync(mask, 0, (size_t)n_nodes * words * 4, stream);

  const int edge_blocks = (n_edges + 255) / 256;              // 1024
  adj_kernel<<<edge_blocks, 256, 0, stream>>>(ei, mask, n_edges, words);

  const int n4 = n_nodes * d_in_dim / 4;
  const int cast_blocks = (n4 + 255) / 256;                   // 4096
  const int tr_blocks = (d_in_dim / 32) * (d_out_dim / 32);   // 256
  prep_kernel<<<cast_blocks + tr_blocks + 1, 256, 0, stream>>>(
      x, xb, n4, W, Wt, d_in_dim, d_out_dim, Hs, dinv, n_nodes,
      cast_blocks, tr_blocks);

  const int nbx = d_out_dim / 128;                            // 4
  const int nbx_sh = 31 - __builtin_clz(nbx);                 // 2
  const int gemm_blocks = nbx * (n_nodes / 64);               // 512
  const int ell_blocks = n_nodes / 4;                         // 2048
  fused_mid_kernel<<<gemm_blocks + ell_blocks, 256, 0, stream>>>(
      xb, Wt, Hs, mask, ell, deg, dinv,
      n_nodes, d_out_dim, d_in_dim, words, gemm_blocks, nbx_sh);

  const int spmm_blocks = 4 * (n_nodes / 16);                 // 2048
  spmm_kernel<<<spmm_blocks, 1024, 0, stream>>>(ell, deg, dinv, Hs, bias, out,
                                                n_nodes, d_out_dim);
}

// Round 12
// 151.513 us; speedup vs baseline: 1.1781x; 1.1781x over previous
//
#include <hip/hip_runtime.h>
#include <hip/hip_bf16.h>

// ---------------------------------------------------------------------------
// GCN layer: out = D^{-1/2} (A_set + I) D^{-1/2} @ (x @ W) + bias
// Pipeline (5 dispatches):
//   memset mask (8MB)
//   fused_front: [adj atomicOr | cast x->bf16 | transpose W | pads]
//     (r10 lesson: the latency-bound atomics hide under the concurrent cast
//      blocks -- de-fusing cost +28us; single atomic pass T<=20us, bucket
//      rewrite NO-GO)
//   deg: mask popc -> dinv only (~3us). Enables pre-scaled GEMM epilogue.
//   fused_mid: [gemm 64x128, epilogue scales row by dinv[row] | build_ell
//     (deg write only -- dinv write removed: gemm blocks read dinv in the
//      same dispatch)]
//   spmm: PRE-SCALED rows -> inner loop has NO dinv_j: 7 inst/iter (was 11,
//     VALU wall 54%Busy at 46us across ALL shape variants r1-r10). ji = bare
//     uint offsets (2KB LDS, 256-thr blocks); quarter-D XCD-pinned gather
//     (L2-resident, FETCH 17MB proven r5/r10); out_i = dinv_i * sum + bias.
// ---------------------------------------------------------------------------

#define ELL_STRIDE 128

typedef __attribute__((ext_vector_type(8))) short bf16x8;
typedef __attribute__((ext_vector_type(4))) float f32x4;
typedef __attribute__((ext_vector_type(2))) float f32x2;

__device__ __forceinline__ unsigned short f2bf(float f) {
  unsigned u = __float_as_uint(f);
  u = (u + 0x7fff + ((u >> 16) & 1)) >> 16;  // RNE
  return (unsigned short)u;
}
__device__ __forceinline__ float bflo(unsigned u) {
  return __uint_as_float(u << 16);
}
__device__ __forceinline__ float bfhi(unsigned u) {
  return __uint_as_float(u & 0xffff0000u);
}

// ---- fused front-end:
// [0,eb): build_adj  [eb,eb+cb): cast  [..+tb): transpose  [last]: pad row
__global__ __launch_bounds__(256) void fused_front_kernel(
    const int* __restrict__ ei, unsigned* __restrict__ mask, int n_edges,
    int words,
    const float* __restrict__ x, unsigned short* __restrict__ xb, int n4,
    const float* __restrict__ W, unsigned short* __restrict__ Wt, int K, int N,
    unsigned short* __restrict__ Hs, int n_nodes,
    int edge_blocks, int cast_blocks, int tr_blocks) {
  const int bid = blockIdx.x;
  if (bid < edge_blocks) {
    const int e = bid * 256 + threadIdx.x;
    if (e < n_edges) {
      const int u = ei[e];
      const int v = ei[e + n_edges];
      // fire-and-forget: never use the return value
      atomicOr(&mask[(size_t)u * words + (v >> 5)], 1u << (v & 31));
      atomicOr(&mask[(size_t)v * words + (u >> 5)], 1u << (u & 31));
    }
    return;
  }
  if (bid < edge_blocks + cast_blocks) {
    const int t = (bid - edge_blocks) * 256 + threadIdx.x;
    if (t < n4) {
      float4 v = ((const float4*)x)[t];
      ushort4 o;
      o.x = f2bf(v.x); o.y = f2bf(v.y); o.z = f2bf(v.z); o.w = f2bf(v.w);
      ((ushort4*)xb)[t] = o;
    }
    return;
  }
  if (bid < edge_blocks + cast_blocks + tr_blocks) {
    // transpose+cast: W[K][N] fp32 -> Wt[N][K] bf16, 32x32 tiles
    __shared__ float tile[32][33];
    const int b = bid - edge_blocks - cast_blocks;
    const int bx = b & ((N >> 5) - 1);
    const int by = b >> (31 - __builtin_clz(N >> 5));
    const int tx = threadIdx.x & 31;
    const int ty = threadIdx.x >> 5;  // 0..7
#pragma unroll
    for (int r = 0; r < 4; ++r)
      tile[ty + 8 * r][tx] = W[(size_t)(by * 32 + ty + 8 * r) * N + bx * 32 + tx];
    __syncthreads();
#pragma unroll
    for (int r = 0; r < 4; ++r)
      Wt[(size_t)(bx * 32 + ty + 8 * r) * K + by * 32 + tx] =
          f2bf(tile[tx][ty + 8 * r]);
    return;
  }
  // zero the ELL pad row Hs[n_nodes][:]
  {
    const int t = threadIdx.x;
    if (t < (N >> 1)) ((unsigned*)(Hs + (size_t)n_nodes * N))[t] = 0;
  }
}

// ---- deg: distinct-neighbor count from the completed mask -> dinv.
// Must be a separate dispatch: gemm (next kernel) reads dinv in its epilogue.
__global__ __launch_bounds__(256) void deg_kernel(
    const unsigned* __restrict__ mask, float* __restrict__ dinv, int words) {
  const int wave = threadIdx.x >> 6, lane = threadIdx.x & 63;
  const int node = blockIdx.x * 4 + wave;
  const unsigned* __restrict__ row = mask + (size_t)node * words;
  int cnt = 0;
  for (int w = lane; w < words; w += 64) cnt += __popc(row[w]);
#pragma unroll
  for (int d = 1; d < 64; d <<= 1) cnt += __shfl_xor(cnt, d, 64);
  if (lane == 0) dinv[node] = rsqrtf((float)cnt + 1.0f);  // + self
}

// ---- fused mid: [0,gb): gemm 64x128 BK=64   [gb..): build_ell (wave/node)
__global__ __launch_bounds__(256) void fused_mid_kernel(
    const unsigned short* __restrict__ xb,  // [M][K] bf16
    const unsigned short* __restrict__ Wt,  // [N][K] bf16
    unsigned short* __restrict__ Hs,        // [M+1][N] bf16, PRE-SCALED rows
    const unsigned* __restrict__ mask, unsigned short* __restrict__ ell,
    int* __restrict__ deg, const float* __restrict__ dinv,
    int M, int N, int K, int words, int gemm_blocks, int nbx_sh) {
  // 64x128 tile, BK=64, 4 waves 2x2, wave tile 32x64 (acc[2][4] 16x16x32).
  // 512 blocks -> 2+ blocks/CU resident. B staged with XOR source
  // pre-swizzle (stride-128B fragment read spans all 8 bank-quads;
  // global_load_lds forces a linear LDS dest so swizzle the source).
  // Epilogue scales row grow by dinv[grow] (pre-scaled-H trick: removes
  // dinv_j from spmm's inner loop entirely).
  __shared__ unsigned short As[512 * 8];
  __shared__ unsigned short Bs[1024 * 8];

  const int tid = threadIdx.x;
  const int bid = blockIdx.x;

  if (bid < gemm_blocks) {
    const int wave = tid >> 6;
    const int lane = tid & 63;
    const int q = lane >> 4;   // quad
    const int c = lane & 15;
    const int bx = bid & ((1 << nbx_sh) - 1);
    const int by = bid >> nbx_sh;
    const int m0 = by * 64;
    const int n0 = bx * 128;
    const int wr = wave >> 1, wc = wave & 1;

    f32x4 acc[2][4] = {};

    for (int k0 = 0; k0 < K; k0 += 64) {
#pragma unroll
      for (int t = 0; t < 2; ++t) {
        const int sbase = t * 256 + wave * 64;
        const int s = sbase + lane;
        const unsigned short* g =
            xb + (size_t)(m0 + (s & 63)) * K + k0 + (s >> 6) * 8;
        __builtin_amdgcn_global_load_lds(
            (const __attribute__((address_space(1))) void*)g,
            (__attribute__((address_space(3))) void*)(As + sbase * 8), 16, 0, 0);
      }
#pragma unroll
      for (int t = 0; t < 4; ++t) {
        const int sbase = t * 256 + wave * 64;
        const int s = sbase + lane;
        const int bn = s >> 3;
        const int bk = (s & 7) ^ (bn & 7);  // XOR-swizzled source (same 128B seg)
        const unsigned short* g =
            Wt + (size_t)(n0 + bn) * K + k0 + bk * 8;
        __builtin_amdgcn_global_load_lds(
            (const __attribute__((address_space(1))) void*)g,
            (__attribute__((address_space(3))) void*)(Bs + sbase * 8), 16, 0, 0);
      }
      __syncthreads();

#pragma unroll
      for (int kk = 0; kk < 2; ++kk) {
        bf16x8 a[2], b[4];
#pragma unroll
        for (int tm = 0; tm < 2; ++tm) {
          const int row = wr * 32 + tm * 16 + c;
          a[tm] = *(const bf16x8*)(As + (((kk * 4 + q) * 64) + row) * 8);
        }
#pragma unroll
        for (int tn = 0; tn < 4; ++tn) {
          const int n = wc * 64 + tn * 16 + c;
          b[tn] = *(const bf16x8*)(Bs + (n * 8 + ((kk * 4 + q) ^ (n & 7))) * 8);
        }
#pragma unroll
        for (int tm = 0; tm < 2; ++tm)
#pragma unroll
          for (int tn = 0; tn < 4; ++tn)
            acc[tm][tn] = __builtin_amdgcn_mfma_f32_16x16x32_bf16(
                a[tm], b[tn], acc[tm][tn], 0, 0, 0);
      }
      __syncthreads();
    }

    // C/D mapping: col=lane&15, row=quad*4+reg ; store PRE-SCALED by dinv
#pragma unroll
    for (int tm = 0; tm < 2; ++tm) {
#pragma unroll
      for (int r = 0; r < 4; ++r) {
        const int grow = m0 + wr * 32 + tm * 16 + q * 4 + r;
        const float dr = dinv[grow];  // L1-hot 32KB table
#pragma unroll
        for (int tn = 0; tn < 4; ++tn) {
          const int gcol = n0 + wc * 64 + tn * 16 + c;
          Hs[(size_t)grow * N + gcol] = f2bf(dr * acc[tm][tn][r]);
        }
      }
    }
    return;
  }

  // ---- build_ell: one wave per node, popcount + lane prefix-scan.
  // dinv write REMOVED (computed by deg_kernel; gemm reads it concurrently).
  {
    const int wave = tid >> 6, lane = tid & 63;
    const int node = (bid - gemm_blocks) * 4 + wave;
    const unsigned* __restrict__ row = mask + (size_t)node * words;
    unsigned short* __restrict__ out = ell + (size_t)node * ELL_STRIDE;

    int running = 0;
    for (int r = 0; r < words; r += 64) {
      const int w = r + lane;
      unsigned bits = row[w];
      const int cnt = __popc(bits);
      int x = cnt;
#pragma unroll
      for (int d = 1; d < 64; d <<= 1) {
        int y = __shfl_up(x, d, 64);
        if (lane >= d) x += y;
      }
      int pos = running + x - cnt;
      while (bits) {
        const int b = __builtin_ctz(bits);
        bits &= bits - 1;
        if (pos < ELL_STRIDE) out[pos] = (unsigned short)((w << 5) + b);
        ++pos;
      }
      running += __shfl(x, 63, 64);
    }
    // self entry at [running], pads (index M -> zero row) after
    for (int p = running + lane; p < ELL_STRIDE; p += 64)
      out[p] = (unsigned short)(p == running ? node : M);
    if (lane == 0) {
      const int dd = running + 1;  // + self
      deg[node] = dd < ELL_STRIDE ? dd : ELL_STRIDE;
    }
  }
}

// ---- spmm: grid 4*(n/4) blocks x 256 thr; wave = one node-quarter.
// qt = bid&3 (bid%8 XCD round-robin -> quarter k on XCDs {k,k+4}, 2.1MB
// L2-resident, FETCH 17MB proven). Rows PRE-SCALED by dinv_j -> loop body
// is ds_read_b32 + add + load + shl/and + 2 v_add = ~7 inst (was 11 and
// 54% VALUBusy at 46us). ji = bare uint byte-offsets, 2KB LDS.
__global__ __launch_bounds__(256) void spmm_kernel(
    const unsigned short* __restrict__ ell, const int* __restrict__ deg,
    const float* __restrict__ dinv, const unsigned short* __restrict__ Hs,
    const float* __restrict__ bias, float* __restrict__ out, int n, int D) {
  __shared__ unsigned ji[4][ELL_STRIDE];
  const int wave = threadIdx.x >> 6, lane = threadIdx.x & 63;
  const int bid = blockIdx.x;
  const int qt = bid & 3;               // quarter, XCD-pinned
  const int i = (bid >> 2) * 4 + wave;  // node
  const unsigned rowbytes = (unsigned)(D * 2);

  {  // stage byte offsets — 2 entries per lane, coalesced
    const unsigned j0 = ell[(size_t)i * ELL_STRIDE + lane];
    const unsigned j1 = ell[(size_t)i * ELL_STRIDE + 64 + lane];
    ji[wave][lane] = j0 * rowbytes;
    ji[wave][64 + lane] = j1 * rowbytes;
  }
  const int d = deg[i];            // includes the self entry
  const float di = dinv[i];
  const int kmax = (d + 7) & ~7;   // ELL pads (zero row) cover the tail

  // this wave reads bytes [qt*256, qt*256+256) of each row: 4B per lane
  const char* __restrict__ hb = (const char*)Hs + qt * 256 + lane * 4;
  float a0 = 0.f, a1 = 0.f;

#pragma unroll 8
  for (int k = 0; k < kmax; ++k) {
    const unsigned off = ji[wave][k];  // uniform addr -> LDS broadcast
    const unsigned hv = *(const unsigned*)(hb + off);
    a0 += bflo(hv);
    a1 += bfhi(hv);
  }

  const int col = qt * (D >> 2) + lane * 2;
  const float2 b = *(const float2*)(bias + col);
  f32x2 o;
  o.x = di * a0 + b.x;
  o.y = di * a1 + b.y;
  __builtin_nontemporal_store(o, (f32x2*)(out + (size_t)i * D + col));
}

extern "C" void kernel_launch(void* const* d_in, const int* in_sizes, int n_in,
                              void* d_out, int out_size, void* d_ws, size_t ws_size,
                              hipStream_t stream) {
  const float* x    = (const float*)d_in[0];
  const int*   ei   = (const int*)d_in[1];
  const float* W    = (const float*)d_in[2];
  const float* bias = (const float*)d_in[3];
  float* out = (float*)d_out;

  const int d_out_dim = in_sizes[3];             // 512
  const int d_in_dim  = in_sizes[2] / d_out_dim; // 512
  const int n_nodes   = in_sizes[0] / d_in_dim;  // 8192
  const int n_edges   = in_sizes[1] / 2;         // 262144
  const int words     = (n_nodes + 31) / 32;     // 256

  // workspace layout (bytes)
  char* ws = (char*)d_ws;
  size_t off = 0;
  unsigned* mask = (unsigned*)(ws + off); off += (size_t)n_nodes * words * 4;       // 8 MB
  int* deg       = (int*)(ws + off);      off += (size_t)n_nodes * 4;               // 32 KB
  float* dinv    = (float*)(ws + off);    off += (size_t)(n_nodes + 1) * 4;         // 32 KB + pad
  unsigned short* ell = (unsigned short*)(ws + off); off += (size_t)n_nodes * ELL_STRIDE * 2; // 2 MB
  unsigned short* xb  = (unsigned short*)(ws + off); off += (size_t)n_nodes * d_in_dim * 2;   // 8 MB
  unsigned short* Wt  = (unsigned short*)(ws + off); off += (size_t)d_in_dim * d_out_dim * 2; // 512 KB
  unsigned short* Hs  = (unsigned short*)(ws + off);
  off += (size_t)(n_nodes + 1) * d_out_dim * 2;  // 8 MB + pad row

  hipMemsetAsync(mask, 0, (size_t)n_nodes * words * 4, stream);

  const int edge_blocks = (n_edges + 255) / 256;              // 1024
  const int n4 = n_nodes * d_in_dim / 4;
  const int cast_blocks = (n4 + 255) / 256;                   // 4096
  const int tr_blocks = (d_in_dim / 32) * (d_out_dim / 32);   // 256
  fused_front_kernel<<<edge_blocks + cast_blocks + tr_blocks + 1, 256, 0, stream>>>(
      ei, mask, n_edges, words, x, xb, n4, W, Wt, d_in_dim, d_out_dim,
      Hs, n_nodes, edge_blocks, cast_blocks, tr_blocks);

  deg_kernel<<<n_nodes / 4, 256, 0, stream>>>(mask, dinv, words);

  const int nbx = d_out_dim / 128;                            // 4
  const int nbx_sh = 31 - __builtin_clz(nbx);                 // 2
  const int gemm_blocks = nbx * (n_nodes / 64);               // 512
  const int ell_blocks = n_nodes / 4;                         // 2048
  fused_mid_kernel<<<gemm_blocks + ell_blocks, 256, 0, stream>>>(
      xb, Wt, Hs, mask, ell, deg, dinv,
      n_nodes, d_out_dim, d_in_dim, words, gemm_blocks, nbx_sh);

  const int spmm_blocks = 4 * (n_nodes / 4);                  // 8192
  spmm_kernel<<<spmm_blocks, 256, 0, stream>>>(ell, deg, dinv, Hs, bias, out,
                                               n_nodes, d_out_dim);
}